// Round 1
// baseline (484.415 us; speedup 1.0000x reference)
//
#include <hip/hip_runtime.h>

#define CH   64     // input channels (= value dim)
#define CPJ  32     // projected channels (= qk dim)
#define HW   4096
#define NB   4
#define RT   64     // rows per block
#define MT   128    // keys per LDS tile
#define NSPLIT 8
#define PSTRIDE 36  // floats; 144 B, 16B-aligned, bank shift 4
#define VSTRIDE 68  // floats; 272 B, 16B-aligned, bank shift 4
#define RSTRIDE 66  // combine buffer stride (bank shift 2 -> free 2-way)

// ---- projection: out[b][n][o] = bias[o] + sum_c W[o][c] * in[b][c][n] ----
__global__ __launch_bounds__(256) void proj_kernel(
    const float* __restrict__ Fq, const float* __restrict__ Fp,
    const float* __restrict__ W,  const float* __restrict__ bias,
    float* __restrict__ qws, float* __restrict__ pws)
{
    __shared__ float Wl[CPJ * CH];
    int tid = threadIdx.x;
    for (int i = tid; i < CPJ * CH; i += 256) Wl[i] = W[i];
    __syncthreads();

    int n = blockIdx.x * 256 + tid;
    int b = blockIdx.y;
    const float* src = blockIdx.z ? Fp : Fq;
    float*       dst = blockIdx.z ? pws : qws;
    const float* in  = src + (size_t)b * CH * HW + n;

    float acc[CPJ];
    #pragma unroll
    for (int o = 0; o < CPJ; ++o) acc[o] = bias[o];

    for (int c = 0; c < CH; ++c) {
        float f = in[(size_t)c * HW];
        #pragma unroll
        for (int o = 0; o < CPJ; ++o) acc[o] += Wl[o * CH + c] * f;
    }

    float* outp = dst + ((size_t)b * HW + n) * CPJ;
    #pragma unroll
    for (int o = 0; o < CPJ; o += 4)
        *reinterpret_cast<float4*>(outp + o) = make_float4(acc[o], acc[o+1], acc[o+2], acc[o+3]);
}

// ---- attention: per (batch, 64-row tile); 8 waves = 8 key-splits ----
__global__ __launch_bounds__(512, 2) void attn_kernel(
    const float* __restrict__ qws, const float* __restrict__ pws,
    const float* __restrict__ Fp,  float* __restrict__ out)
{
    __shared__ float p_tile[MT * PSTRIDE];   // 18432 B
    __shared__ float v_tile[MT * VSTRIDE];   // 34816 B
    float* red = p_tile;                     // reused in epilogue (64*66=4224 floats <= 4608)

    int tid   = threadIdx.x;
    int row   = tid & 63;
    int split = tid >> 6;        // 0..7, one wave per split
    int b     = blockIdx.y;
    int n0    = blockIdx.x * RT;
    int n     = n0 + row;

    // q row -> registers
    float q[CPJ];
    const float* qp = qws + ((size_t)b * HW + n) * CPJ;
    #pragma unroll
    for (int o = 0; o < CPJ; o += 4) {
        float4 v4 = *reinterpret_cast<const float4*>(qp + o);
        q[o] = v4.x; q[o+1] = v4.y; q[o+2] = v4.z; q[o+3] = v4.w;
    }

    float O[CH];
    #pragma unroll
    for (int c = 0; c < CH; ++c) O[c] = 0.f;
    float l = 0.f;

    const float* pbase = pws + (size_t)b * HW * CPJ;
    const float* vbase = Fp  + (size_t)b * CH * HW;

    for (int m0 = 0; m0 < HW; m0 += MT) {
        __syncthreads();  // previous tile fully consumed
        // stage p tile: thread t -> key m=t>>2, channels (t&3)*8 .. +8
        {
            int m  = tid >> 2;
            int o0 = (tid & 3) * 8;
            const float* srcp = pbase + (size_t)(m0 + m) * CPJ + o0;
            float4 a0 = *reinterpret_cast<const float4*>(srcp);
            float4 a1 = *reinterpret_cast<const float4*>(srcp + 4);
            float* d = p_tile + m * PSTRIDE + o0;
            *reinterpret_cast<float4*>(d)     = a0;
            *reinterpret_cast<float4*>(d + 4) = a1;
        }
        // stage v tile (transpose [c][m] -> [m][c]); coalesced global reads
        #pragma unroll
        for (int rep = 0; rep < 16; ++rep) {
            int i = rep * 512 + tid;
            int c = i >> 7;
            int m = i & 127;
            v_tile[m * VSTRIDE + c] = vbase[(size_t)c * HW + m0 + m];
        }
        __syncthreads();

        int mbase = split * 16;
        #pragma unroll 4
        for (int k = 0; k < 16; ++k) {
            const float* pr = p_tile + (mbase + k) * PSTRIDE;  // broadcast reads
            float s0 = 0.f, s1 = 0.f, s2 = 0.f, s3 = 0.f;
            #pragma unroll
            for (int o = 0; o < CPJ; o += 4) {
                s0 += q[o]   * pr[o];
                s1 += q[o+1] * pr[o+1];
                s2 += q[o+2] * pr[o+2];
                s3 += q[o+3] * pr[o+3];
            }
            float e = __expf((s0 + s1) + (s2 + s3));  // no max needed: |s| <~ 40
            l += e;
            const float* vr = v_tile + (mbase + k) * VSTRIDE;  // broadcast reads
            #pragma unroll
            for (int c = 0; c < CH; ++c) O[c] += e * vr[c];
        }
    }

    // ---- combine the 8 splits via LDS (sequential, one-time) ----
    __syncthreads();
    if (split == 0) {
        float* r = red + row * RSTRIDE;
        #pragma unroll
        for (int c = 0; c < CH; ++c) r[c] = O[c];
        r[CH] = l;
    }
    __syncthreads();
    for (int s = 1; s < NSPLIT; ++s) {
        if (split == s) {
            float* r = red + row * RSTRIDE;
            #pragma unroll
            for (int c = 0; c < CH; ++c) r[c] += O[c];
            r[CH] += l;
        }
        __syncthreads();
    }

    // ---- write out[b][c][n0+row] = O[c]/l ; wave-uniform c -> coalesced ----
    float* ob = out + (size_t)b * CH * HW + n0;
    #pragma unroll
    for (int c0 = 0; c0 < CH; c0 += 8) {
        int c = c0 + split;
        float inv = 1.0f / red[row * RSTRIDE + CH];
        ob[(size_t)c * HW + row] = red[row * RSTRIDE + c] * inv;
    }
}

extern "C" void kernel_launch(void* const* d_in, const int* in_sizes, int n_in,
                              void* d_out, int out_size, void* d_ws, size_t ws_size,
                              hipStream_t stream)
{
    const float* Fq   = (const float*)d_in[0];
    const float* Fp   = (const float*)d_in[1];
    const float* W    = (const float*)d_in[2];
    const float* bias = (const float*)d_in[3];
    float* out = (float*)d_out;

    float* qws = (float*)d_ws;                          // [4][4096][32]
    float* pws = qws + (size_t)NB * HW * CPJ;           // [4][4096][32]  (4 MB total)

    dim3 pgrid(HW / 256, NB, 2);
    proj_kernel<<<pgrid, 256, 0, stream>>>(Fq, Fp, W, bias, qws, pws);

    dim3 agrid(HW / RT, NB);
    attn_kernel<<<agrid, 512, 0, stream>>>(qws, pws, Fp, out);
}

// Round 3
// 61.107 us; speedup vs baseline: 7.9273x; 7.9273x over previous
//
#include <hip/hip_runtime.h>

#define HW 4096
#define LOG2E 1.44269504088896340736f

typedef _Float16 half8  __attribute__((ext_vector_type(8)));
typedef __bf16   bf16x8 __attribute__((ext_vector_type(8)));
typedef float    f32x16 __attribute__((ext_vector_type(16)));

static __device__ __forceinline__ float fexp2(float x) {
    return exp2f(x);
}

static __device__ __forceinline__ unsigned cvtpk_bf16(float lo, float hi) {
    unsigned r;
    asm("v_cvt_pk_bf16_f32 %0, %1, %2" : "=v"(r) : "v"(lo), "v"(hi));
    return r;
}

static __device__ __forceinline__ f32x16 mfma16(uint4 a, uint4 b, f32x16 c) {
    return __builtin_amdgcn_mfma_f32_32x32x16_f16(
        __builtin_bit_cast(half8, a), __builtin_bit_cast(half8, b), c, 0, 0, 0);
}
static __device__ __forceinline__ f32x16 mfmab16(uint4 a, uint4 b, f32x16 c) {
    return __builtin_amdgcn_mfma_f32_32x32x16_bf16(
        __builtin_bit_cast(bf16x8, a), __builtin_bit_cast(bf16x8, b), c, 0, 0, 0);
}

// ---- projection: q (fp16, scaled by log2e, plain [b][n][32]) and
// ----             p (fp16, MFMA-A fragment order [b][kt][chunk][lane][8]) ----
__global__ __launch_bounds__(128) void proj_kernel(
    const float* __restrict__ Fq, const float* __restrict__ Fp,
    const float* __restrict__ W, const float* __restrict__ bias,
    _Float16* __restrict__ q_ws, char* __restrict__ p_arr)
{
    __shared__ float Wl[2048];
    int tid = threadIdx.x;
    for (int i = tid; i < 2048; i += 128) Wl[i] = W[i];
    __syncthreads();

    int n = blockIdx.x * 128 + tid;
    int b = blockIdx.y;
    int isP = blockIdx.z;
    const float* in = (isP ? Fp : Fq) + (size_t)(b * 64) * HW + n;

    float acc[32];
    #pragma unroll
    for (int o = 0; o < 32; ++o) acc[o] = bias[o];
    for (int c = 0; c < 64; ++c) {
        float f = in[(size_t)c * HW];
        #pragma unroll
        for (int o = 0; o < 32; ++o) acc[o] += Wl[o * 64 + c] * f;
    }

    if (!isP) {
        _Float16* dst = q_ws + ((size_t)(b * HW + n) << 5);
        #pragma unroll
        for (int g = 0; g < 4; ++g) {
            union { _Float16 h[8]; uint4 u; } pk;
            #pragma unroll
            for (int j = 0; j < 8; ++j) pk.h[j] = (_Float16)(acc[g * 8 + j] * LOG2E);
            *(uint4*)(dst + g * 8) = pk.u;
        }
    } else {
        int kt = n >> 5, ln = n & 31;
        #pragma unroll
        for (int chunk = 0; chunk < 2; ++chunk) {
            #pragma unroll
            for (int h2 = 0; h2 < 2; ++h2) {
                union { _Float16 h[8]; uint4 u; } pk;
                #pragma unroll
                for (int j = 0; j < 8; ++j) pk.h[j] = (_Float16)acc[chunk * 16 + h2 * 8 + j];
                size_t off = (((size_t)((b * 128 + kt) * 2 + chunk)) << 9) + (size_t)((h2 << 5) + ln) * 8;
                *(uint4*)(p_arr + off * 2) = pk.u;
            }
        }
    }
}

// ---- V: fp32 [b][c][m] -> bf16 B-fragment, key order matched to the
// ---- QK^T C-output key order: slot (hi, j) holds key 4*hi + (j&3) + 8*(j>>2).
// ---- Array: [b][mt][chalf][chunk][lane=hi*32+c5][8 elems] ----
__global__ __launch_bounds__(256) void vprep_kernel(
    const float* __restrict__ Fp, char* __restrict__ v_arr)
{
    int id = blockIdx.x * 256 + threadIdx.x;      // 131072 total
    int mg = id & 511, c = (id >> 9) & 63, b = id >> 15;
    const float* src = Fp + ((size_t)(b * 64 + c) << 12) + (mg << 3);
    float4 f0 = *(const float4*)src;          // keys mc+0..3 (mc = 8*(mg&1))
    float4 f1 = *(const float4*)(src + 4);    // keys mc+4..7
    uint2 o0 = make_uint2(cvtpk_bf16(f0.x, f0.y), cvtpk_bf16(f0.z, f0.w)); // -> hi=0 lane
    uint2 o1 = make_uint2(cvtpk_bf16(f1.x, f1.y), cvtpk_bf16(f1.z, f1.w)); // -> hi=1 lane
    int mt = mg >> 2, chunk = (mg >> 1) & 1, hsel = mg & 1;
    int chalf = c >> 5, c5 = c & 31;
    size_t tilebase = ((size_t)(((b * 128 + mt) * 2 + chalf) * 2 + chunk)) << 10; // 64 lanes * 16B
    char* d0 = v_arr + tilebase + (size_t)c5 * 16 + hsel * 8;
    char* d1 = v_arr + tilebase + (size_t)(32 + c5) * 16 + hsel * 8;
    *(uint2*)d0 = o0;
    *(uint2*)d1 = o1;
}

// A-fragment build: slot (hi, j) must hold key kappa(hi,j) = 4hi + (j&3) + 8*(j>>2),
// which is exactly crow(j, hi) from the QK^T C-output -> direct per-lane pack, no
// cross-lane ops. V was prepped with the identical slot->key map, so PV contracts
// correctly regardless of the hardware's internal k-slot ordering (bijection).
#define SOFTPART(S, A0, A1, LA, LB) { \
    float e0=fexp2(S[0]),  e1=fexp2(S[1]),  e2=fexp2(S[2]),  e3=fexp2(S[3]); \
    float e4=fexp2(S[4]),  e5=fexp2(S[5]),  e6=fexp2(S[6]),  e7=fexp2(S[7]); \
    float e8=fexp2(S[8]),  e9=fexp2(S[9]),  e10=fexp2(S[10]), e11=fexp2(S[11]); \
    float e12=fexp2(S[12]), e13=fexp2(S[13]), e14=fexp2(S[14]), e15=fexp2(S[15]); \
    LA += ((e0+e1)+(e2+e3)) + ((e4+e5)+(e6+e7)); \
    LB += ((e8+e9)+(e10+e11)) + ((e12+e13)+(e14+e15)); \
    A0 = make_uint4(cvtpk_bf16(e0,e1),  cvtpk_bf16(e2,e3),  cvtpk_bf16(e4,e5),  cvtpk_bf16(e6,e7)); \
    A1 = make_uint4(cvtpk_bf16(e8,e9),  cvtpk_bf16(e10,e11), cvtpk_bf16(e12,e13), cvtpk_bf16(e14,e15)); \
}

#define TILE(P0,P1,V00,V01,V10,V11) { \
    f32x16 s0 = (f32x16)0.0f, s1 = (f32x16)0.0f; \
    s0 = mfma16(P0, q00, s0); s0 = mfma16(P1, q01, s0); \
    s1 = mfma16(P0, q10, s1); s1 = mfma16(P1, q11, s1); \
    uint4 A0, A1; \
    SOFTPART(s0, A0, A1, l0a, l0b) \
    o00 = mfmab16(A0, V00, o00); o00 = mfmab16(A1, V01, o00); \
    o01 = mfmab16(A0, V10, o01); o01 = mfmab16(A1, V11, o01); \
    SOFTPART(s1, A0, A1, l1a, l1b) \
    o10 = mfmab16(A0, V00, o10); o10 = mfmab16(A1, V01, o10); \
    o11 = mfmab16(A0, V10, o11); o11 = mfmab16(A1, V11, o11); \
}

__global__ __launch_bounds__(512, 2) void attn_kernel(
    const _Float16* __restrict__ q_ws, const char* __restrict__ p_arr,
    const char* __restrict__ v_arr, float* __restrict__ out)
{
    __shared__ float part[8][32][33];
    __shared__ float l_red[8][2][64];
    __shared__ float l_inv[64];

    const int tid  = threadIdx.x;
    const int lane = tid & 63;
    const int w    = tid >> 6;       // wave = key split (512 keys each)
    const int lo5  = lane & 31;
    const int hi   = lane >> 5;
    const int b    = blockIdx.y;
    const int qb   = blockIdx.x << 6;

    // Q fragments: 2 q-subtiles x 2 k-chunks, hoisted
    uint4 q00, q01, q10, q11;
    {
        const _Float16* qp = q_ws + (((size_t)(b * HW) + qb + lo5) << 5) + (hi << 3);
        q00 = *(const uint4*)qp;
        q01 = *(const uint4*)(qp + 16);
        q10 = *(const uint4*)(qp + 1024);
        q11 = *(const uint4*)(qp + 1040);
    }

    const char* pb = p_arr + ((size_t)(b * 128 + w * 16) << 11) + (lane << 4);
    const char* vb = v_arr + ((size_t)(b * 128 + w * 16) << 12) + (lane << 4);

    f32x16 o00 = (f32x16)0.0f, o01 = (f32x16)0.0f, o10 = (f32x16)0.0f, o11 = (f32x16)0.0f;
    float l0a = 0.f, l0b = 0.f, l1a = 0.f, l1b = 0.f;

    uint4 pA0, pA1, vA00, vA01, vA10, vA11;
    uint4 pB0, pB1, vB00, vB01, vB10, vB11;

#define LOADT(P0,P1,V00,V01,V10,V11,T) { \
    const char* pp = pb + ((size_t)(T) << 11); \
    P0 = *(const uint4*)pp; P1 = *(const uint4*)(pp + 1024); \
    const char* vp = vb + ((size_t)(T) << 12); \
    V00 = *(const uint4*)vp;          V01 = *(const uint4*)(vp + 1024); \
    V10 = *(const uint4*)(vp + 2048); V11 = *(const uint4*)(vp + 3072); }

    LOADT(pA0, pA1, vA00, vA01, vA10, vA11, 0)
    for (int i = 0; i < 8; ++i) {
        int t = 2 * i + 1;
        LOADT(pB0, pB1, vB00, vB01, vB10, vB11, t)
        TILE(pA0, pA1, vA00, vA01, vA10, vA11)
        int t2 = (t + 1 > 15) ? 15 : (t + 1);
        LOADT(pA0, pA1, vA00, vA01, vA10, vA11, t2)
        TILE(pB0, pB1, vB00, vB01, vB10, vB11)
    }

    // ---- epilogue: combine 8 key-split waves ----
    l_red[w][0][lane] = l0a + l0b;
    l_red[w][1][lane] = l1a + l1b;
    __syncthreads();
    if (tid < 64) {
        int s_ = tid >> 5, qq = tid & 31;
        float sum = 0.f;
        #pragma unroll
        for (int w2 = 0; w2 < 8; ++w2)
            sum += l_red[w2][s_][qq] + l_red[w2][s_][qq + 32];
        l_inv[tid] = 1.0f / sum;
    }

#define EPIPASS(OC, S_, H_) { \
    __syncthreads(); \
    _Pragma("unroll") \
    for (int r = 0; r < 16; ++r) \
        part[w][(r & 3) + 8 * (r >> 2) + 4 * hi][lo5] = OC[r]; \
    __syncthreads(); \
    _Pragma("unroll") \
    for (int rep = 0; rep < 2; ++rep) { \
        int idx = rep * 512 + tid; \
        int c_ = idx >> 5, q_ = idx & 31; \
        float v_ = ((part[0][q_][c_] + part[1][q_][c_]) + (part[2][q_][c_] + part[3][q_][c_])) \
                 + ((part[4][q_][c_] + part[5][q_][c_]) + (part[6][q_][c_] + part[7][q_][c_])); \
        out[((size_t)(((b << 6) + ((H_) << 5) + c_)) << 12) + qb + ((S_) << 5) + q_] = v_ * l_inv[((S_) << 5) + q_]; \
    } \
}

    EPIPASS(o00, 0, 0)
    EPIPASS(o01, 0, 1)
    EPIPASS(o10, 1, 0)
    EPIPASS(o11, 1, 1)
}

extern "C" void kernel_launch(void* const* d_in, const int* in_sizes, int n_in,
                              void* d_out, int out_size, void* d_ws, size_t ws_size,
                              hipStream_t stream)
{
    const float* Fq = (const float*)d_in[0];
    const float* Fp = (const float*)d_in[1];
    const float* W  = (const float*)d_in[2];
    const float* bs = (const float*)d_in[3];
    float* out = (float*)d_out;

    _Float16* q_ws = (_Float16*)d_ws;               // 1 MB
    char* p_arr = (char*)d_ws + (1 << 20);          // 1 MB
    char* v_arr = (char*)d_ws + (2 << 20);          // 2 MB

    proj_kernel<<<dim3(32, 4, 2), 128, 0, stream>>>(Fq, Fp, W, bs, q_ws, p_arr);
    vprep_kernel<<<512, 256, 0, stream>>>(Fp, v_arr);
    attn_kernel<<<dim3(64, 4), 512, 0, stream>>>(q_ws, p_arr, v_arr, out);
}

// Round 6
// 51.291 us; speedup vs baseline: 9.4445x; 1.1914x over previous
//
#include <hip/hip_runtime.h>

#define HW 4096
#define LOG2E 1.44269504088896340736f

typedef _Float16 half8  __attribute__((ext_vector_type(8)));
typedef __bf16   bf16x8 __attribute__((ext_vector_type(8)));
typedef float    f32x16 __attribute__((ext_vector_type(16)));

// NOTE: __builtin_amdgcn_exp2f is empirically NOT 2^x here (rounds 2/4/5 all
// failed with identical absmax 3.479065 whenever it was used; round 3 with
// exp2f passed). Keep libm exp2f.
static __device__ __forceinline__ float fexp2(float x) {
    return exp2f(x);
}

static __device__ __forceinline__ unsigned cvtpk_bf16(float lo, float hi) {
    unsigned r;
    asm("v_cvt_pk_bf16_f32 %0, %1, %2" : "=v"(r) : "v"(lo), "v"(hi));
    return r;
}

static __device__ __forceinline__ f32x16 mfma16(uint4 a, uint4 b, f32x16 c) {
    return __builtin_amdgcn_mfma_f32_32x32x16_f16(
        __builtin_bit_cast(half8, a), __builtin_bit_cast(half8, b), c, 0, 0, 0);
}
static __device__ __forceinline__ f32x16 mfmab16(uint4 a, uint4 b, f32x16 c) {
    return __builtin_amdgcn_mfma_f32_32x32x16_bf16(
        __builtin_bit_cast(bf16x8, a), __builtin_bit_cast(bf16x8, b), c, 0, 0, 0);
}

// ---- projection: q (fp16, scaled by log2e, plain [b][n][32]) and
// ----             p (fp16, MFMA-A fragment order [b][kt][chunk][lane][8]) ----
__global__ __launch_bounds__(128) void proj_kernel(
    const float* __restrict__ Fq, const float* __restrict__ Fp,
    const float* __restrict__ W, const float* __restrict__ bias,
    _Float16* __restrict__ q_ws, char* __restrict__ p_arr)
{
    __shared__ float Wl[2048];
    int tid = threadIdx.x;
    for (int i = tid; i < 2048; i += 128) Wl[i] = W[i];
    __syncthreads();

    int n = blockIdx.x * 128 + tid;
    int b = blockIdx.y;
    int isP = blockIdx.z;
    const float* in = (isP ? Fp : Fq) + (size_t)(b * 64) * HW + n;

    float acc[32];
    #pragma unroll
    for (int o = 0; o < 32; ++o) acc[o] = bias[o];
    for (int c = 0; c < 64; ++c) {
        float f = in[(size_t)c * HW];
        #pragma unroll
        for (int o = 0; o < 32; ++o) acc[o] += Wl[o * 64 + c] * f;
    }

    if (!isP) {
        _Float16* dst = q_ws + ((size_t)(b * HW + n) << 5);
        #pragma unroll
        for (int g = 0; g < 4; ++g) {
            union { _Float16 h[8]; uint4 u; } pk;
            #pragma unroll
            for (int j = 0; j < 8; ++j) pk.h[j] = (_Float16)(acc[g * 8 + j] * LOG2E);
            *(uint4*)(dst + g * 8) = pk.u;
        }
    } else {
        int kt = n >> 5, ln = n & 31;
        #pragma unroll
        for (int chunk = 0; chunk < 2; ++chunk) {
            #pragma unroll
            for (int h2 = 0; h2 < 2; ++h2) {
                union { _Float16 h[8]; uint4 u; } pk;
                #pragma unroll
                for (int j = 0; j < 8; ++j) pk.h[j] = (_Float16)acc[chunk * 16 + h2 * 8 + j];
                size_t off = (((size_t)((b * 128 + kt) * 2 + chunk)) << 9) + (size_t)((h2 << 5) + ln) * 8;
                *(uint4*)(p_arr + off * 2) = pk.u;
            }
        }
    }
}

// ---- V: fp32 [b][c][m] -> bf16 B-fragment, key order matched to the
// ---- QK^T C-output key order: slot (hi, j) holds key 4*hi + (j&3) + 8*(j>>2).
// ---- Array: [b][mt][chalf][chunk][lane=hi*32+c5][8 elems] ----
__global__ __launch_bounds__(256) void vprep_kernel(
    const float* __restrict__ Fp, char* __restrict__ v_arr)
{
    int id = blockIdx.x * 256 + threadIdx.x;      // 131072 total
    int mg = id & 511, c = (id >> 9) & 63, b = id >> 15;
    const float* src = Fp + ((size_t)(b * 64 + c) << 12) + (mg << 3);
    float4 f0 = *(const float4*)src;          // keys mc+0..3 (mc = 8*(mg&1))
    float4 f1 = *(const float4*)(src + 4);    // keys mc+4..7
    uint2 o0 = make_uint2(cvtpk_bf16(f0.x, f0.y), cvtpk_bf16(f0.z, f0.w)); // -> hi=0 lane
    uint2 o1 = make_uint2(cvtpk_bf16(f1.x, f1.y), cvtpk_bf16(f1.z, f1.w)); // -> hi=1 lane
    int mt = mg >> 2, chunk = (mg >> 1) & 1, hsel = mg & 1;
    int chalf = c >> 5, c5 = c & 31;
    size_t tilebase = ((size_t)(((b * 128 + mt) * 2 + chalf) * 2 + chunk)) << 10; // 64 lanes * 16B
    char* d0 = v_arr + tilebase + (size_t)c5 * 16 + hsel * 8;
    char* d1 = v_arr + tilebase + (size_t)(32 + c5) * 16 + hsel * 8;
    *(uint2*)d0 = o0;
    *(uint2*)d1 = o1;
}

// A-fragment build: slot (hi, j) holds key kappa(hi,j) = 4hi + (j&3) + 8*(j>>2) =
// exactly the QK^T C-output key order; V prepped with the same map -> PV contracts
// correctly regardless of the hardware's internal k-slot ordering (bijection).
#define SOFTPART(S, A0, A1, LA, LB) { \
    float e0=fexp2(S[0]),  e1=fexp2(S[1]),  e2=fexp2(S[2]),  e3=fexp2(S[3]); \
    float e4=fexp2(S[4]),  e5=fexp2(S[5]),  e6=fexp2(S[6]),  e7=fexp2(S[7]); \
    float e8=fexp2(S[8]),  e9=fexp2(S[9]),  e10=fexp2(S[10]), e11=fexp2(S[11]); \
    float e12=fexp2(S[12]), e13=fexp2(S[13]), e14=fexp2(S[14]), e15=fexp2(S[15]); \
    LA += ((e0+e1)+(e2+e3)) + ((e4+e5)+(e6+e7)); \
    LB += ((e8+e9)+(e10+e11)) + ((e12+e13)+(e14+e15)); \
    A0 = make_uint4(cvtpk_bf16(e0,e1),  cvtpk_bf16(e2,e3),  cvtpk_bf16(e4,e5),  cvtpk_bf16(e6,e7)); \
    A1 = make_uint4(cvtpk_bf16(e8,e9),  cvtpk_bf16(e10,e11), cvtpk_bf16(e12,e13), cvtpk_bf16(e14,e15)); \
}

#define TILE(P0,P1,V00,V01,V10,V11) { \
    f32x16 s0 = (f32x16)0.0f, s1 = (f32x16)0.0f; \
    s0 = mfma16(P0, q00, s0); s0 = mfma16(P1, q01, s0); \
    s1 = mfma16(P0, q10, s1); s1 = mfma16(P1, q11, s1); \
    uint4 A0, A1; \
    SOFTPART(s0, A0, A1, l0a, l0b) \
    o00 = mfmab16(A0, V00, o00); o00 = mfmab16(A1, V01, o00); \
    o01 = mfmab16(A0, V10, o01); o01 = mfmab16(A1, V11, o01); \
    SOFTPART(s1, A0, A1, l1a, l1b) \
    o10 = mfmab16(A0, V00, o10); o10 = mfmab16(A1, V01, o10); \
    o11 = mfmab16(A0, V10, o11); o11 = mfmab16(A1, V11, o11); \
}

__global__ __launch_bounds__(512, 2) void attn_kernel(
    const _Float16* __restrict__ q_ws, const char* __restrict__ p_arr,
    const char* __restrict__ v_arr, float* __restrict__ out)
{
    __shared__ float part[8][32][33];
    __shared__ float l_red[8][2][64];
    __shared__ float l_inv[64];

    const int tid  = threadIdx.x;
    const int lane = tid & 63;
    const int w    = tid >> 6;       // wave = key split (512 keys each)
    const int lo5  = lane & 31;
    const int hi   = lane >> 5;

    // XCD-aware swizzle: id%8 = XCD (m09); XCD pair {2b,2b+1} <- batch b,
    // so each XCD's L2 holds one batch's ~1MB q/p/v working set.
    // Bijective: id bits [0]|[3:7] -> q-tile, bits [1:2] -> batch.
    const int id   = blockIdx.x + (blockIdx.y << 6);
    const int b    = (id >> 1) & 3;
    const int qb   = (((id >> 3) << 1) | (id & 1)) << 6;

    // Q fragments: 2 q-subtiles x 2 k-chunks, hoisted
    uint4 q00, q01, q10, q11;
    {
        const _Float16* qp = q_ws + (((size_t)(b * HW) + qb + lo5) << 5) + (hi << 3);
        q00 = *(const uint4*)qp;
        q01 = *(const uint4*)(qp + 16);
        q10 = *(const uint4*)(qp + 1024);
        q11 = *(const uint4*)(qp + 1040);
    }

    const char* pb = p_arr + ((size_t)(b * 128 + w * 16) << 11) + (lane << 4);
    const char* vb = v_arr + ((size_t)(b * 128 + w * 16) << 12) + (lane << 4);

    f32x16 o00 = (f32x16)0.0f, o01 = (f32x16)0.0f, o10 = (f32x16)0.0f, o11 = (f32x16)0.0f;
    float l0a = 0.f, l0b = 0.f, l1a = 0.f, l1b = 0.f;

    uint4 pA0, pA1, vA00, vA01, vA10, vA11;
    uint4 pB0, pB1, vB00, vB01, vB10, vB11;

#define LOADT(P0,P1,V00,V01,V10,V11,T) { \
    const char* pp = pb + ((size_t)(T) << 11); \
    P0 = *(const uint4*)pp; P1 = *(const uint4*)(pp + 1024); \
    const char* vp = vb + ((size_t)(T) << 12); \
    V00 = *(const uint4*)vp;          V01 = *(const uint4*)(vp + 1024); \
    V10 = *(const uint4*)(vp + 2048); V11 = *(const uint4*)(vp + 3072); }

    LOADT(pA0, pA1, vA00, vA01, vA10, vA11, 0)
    for (int i = 0; i < 8; ++i) {
        int t = 2 * i + 1;
        LOADT(pB0, pB1, vB00, vB01, vB10, vB11, t)
        TILE(pA0, pA1, vA00, vA01, vA10, vA11)
        int t2 = (t + 1 > 15) ? 15 : (t + 1);
        LOADT(pA0, pA1, vA00, vA01, vA10, vA11, t2)
        TILE(pB0, pB1, vB00, vB01, vB10, vB11)
    }

    // ---- epilogue: combine 8 key-split waves ----
    l_red[w][0][lane] = l0a + l0b;
    l_red[w][1][lane] = l1a + l1b;
    __syncthreads();
    if (tid < 64) {
        int s_ = tid >> 5, qq = tid & 31;
        float sum = 0.f;
        #pragma unroll
        for (int w2 = 0; w2 < 8; ++w2)
            sum += l_red[w2][s_][qq] + l_red[w2][s_][qq + 32];
        l_inv[tid] = 1.0f / sum;
    }

#define EPIPASS(OC, S_, H_) { \
    __syncthreads(); \
    _Pragma("unroll") \
    for (int r = 0; r < 16; ++r) \
        part[w][(r & 3) + 8 * (r >> 2) + 4 * hi][lo5] = OC[r]; \
    __syncthreads(); \
    _Pragma("unroll") \
    for (int rep = 0; rep < 2; ++rep) { \
        int idx = rep * 512 + tid; \
        int c_ = idx >> 5, q_ = idx & 31; \
        float v_ = ((part[0][q_][c_] + part[1][q_][c_]) + (part[2][q_][c_] + part[3][q_][c_])) \
                 + ((part[4][q_][c_] + part[5][q_][c_]) + (part[6][q_][c_] + part[7][q_][c_])); \
        out[((size_t)(((b << 6) + ((H_) << 5) + c_)) << 12) + qb + ((S_) << 5) + q_] = v_ * l_inv[((S_) << 5) + q_]; \
    } \
}

    EPIPASS(o00, 0, 0)
    EPIPASS(o01, 0, 1)
    EPIPASS(o10, 1, 0)
    EPIPASS(o11, 1, 1)
}

extern "C" void kernel_launch(void* const* d_in, const int* in_sizes, int n_in,
                              void* d_out, int out_size, void* d_ws, size_t ws_size,
                              hipStream_t stream)
{
    const float* Fq = (const float*)d_in[0];
    const float* Fp = (const float*)d_in[1];
    const float* W  = (const float*)d_in[2];
    const float* bs = (const float*)d_in[3];
    float* out = (float*)d_out;

    _Float16* q_ws = (_Float16*)d_ws;               // 1 MB
    char* p_arr = (char*)d_ws + (1 << 20);          // 1 MB
    char* v_arr = (char*)d_ws + (2 << 20);          // 2 MB

    proj_kernel<<<dim3(32, 4, 2), 128, 0, stream>>>(Fq, Fp, W, bs, q_ws, p_arr);
    vprep_kernel<<<512, 256, 0, stream>>>(Fp, v_arr);
    attn_kernel<<<dim3(64, 4), 512, 0, stream>>>(q_ws, p_arr, v_arr, out);
}

// Round 7
// 30.734 us; speedup vs baseline: 15.7618x; 1.6689x over previous
//
#include <hip/hip_runtime.h>

#define HW 4096

typedef _Float16 half8  __attribute__((ext_vector_type(8)));
typedef __bf16   bf16x8 __attribute__((ext_vector_type(8)));
typedef float    f32x16 __attribute__((ext_vector_type(16)));

// NOTE: __builtin_amdgcn_exp2f is empirically NOT 2^x here (rounds 2/4/5
// failed with identical absmax 3.479065 whenever used; exp2f/__expf pass).
// __expf = native exp (1 mul + v_exp_f32), proven correct in round 1.
static __device__ __forceinline__ float fexp(float x) {
    return __expf(x);
}

static __device__ __forceinline__ unsigned cvtpk_bf16(float lo, float hi) {
    unsigned r;
    asm("v_cvt_pk_bf16_f32 %0, %1, %2" : "=v"(r) : "v"(lo), "v"(hi));
    return r;
}

static __device__ __forceinline__ f32x16 mfma16(uint4 a, uint4 b, f32x16 c) {
    return __builtin_amdgcn_mfma_f32_32x32x16_f16(
        __builtin_bit_cast(half8, a), __builtin_bit_cast(half8, b), c, 0, 0, 0);
}
static __device__ __forceinline__ f32x16 mfmab16(uint4 a, uint4 b, f32x16 c) {
    return __builtin_amdgcn_mfma_f32_32x32x16_bf16(
        __builtin_bit_cast(bf16x8, a), __builtin_bit_cast(bf16x8, b), c, 0, 0, 0);
}

// ---- unified prep: grid (192, 4). Proven output-equivalent to the split
// ---- proj/vprep kernels by the round-4/5 absmax identity (sole round-4 bug
// ---- was the exp builtin). q is now written UNSCALED (attn uses __expf).
// x in [0,64): projection (x<32: q, else p), c-split-2, 128 n per block.
// x in [64,192): V B-fragment prep for tile mt = x-64, coalesced 16B stores.
__global__ __launch_bounds__(256) void prep_kernel(
    const float* __restrict__ Fq, const float* __restrict__ Fp,
    const float* __restrict__ W,  const float* __restrict__ bias,
    _Float16* __restrict__ q_ws, char* __restrict__ p_arr, char* __restrict__ v_arr)
{
    const int tid = threadIdx.x;
    const int b   = blockIdx.y;
    const int x   = blockIdx.x;

    if (x >= 64) {
        // ---- V prep: slot (hi,j) <- key 32*mt + 16*chunk + 4*hi + (j&3) + 8*(j>>2) ----
        int mt = x - 64;
        int c5 = tid & 31, hi = (tid >> 5) & 1, chunk = (tid >> 6) & 1, chalf = tid >> 7;
        int c = chalf * 32 + c5;
        int m = mt * 32 + chunk * 16 + hi * 4;
        const float* src = Fp + ((size_t)(b * 64 + c) << 12) + m;
        float4 f0 = *(const float4*)src;        // keys m..m+3   -> j=0..3
        float4 f1 = *(const float4*)(src + 8);  // keys m+8..m+11-> j=4..7
        uint4 o = make_uint4(cvtpk_bf16(f0.x, f0.y), cvtpk_bf16(f0.z, f0.w),
                             cvtpk_bf16(f1.x, f1.y), cvtpk_bf16(f1.z, f1.w));
        size_t tb = ((size_t)(((b * 128 + mt) * 2 + chalf) * 2 + chunk)) << 10;
        *(uint4*)(v_arr + tb + (size_t)((hi << 5) | c5) * 16) = o;   // consecutive lanes -> consecutive 16B
        return;
    }

    // ---- projection, c-split-2 ----
    __shared__ float Wt[64][36];     // transposed W, 16B-aligned rows, wave-uniform float4 reads
    __shared__ float comb[128][33];  // chalf-combine

    for (int i = tid; i < 2048; i += 256)
        Wt[i & 63][i >> 6] = W[i];   // W[o][c] flat: o=i>>6, c=i&63 (coalesced read)
    __syncthreads();

    const int isP   = x >> 5;
    const int nl    = tid & 127;
    const int chalf = tid >> 7;
    const int n     = ((x & 31) << 7) + nl;
    const float* in = (isP ? Fp : Fq) + (size_t)(b * 64 + chalf * 32) * HW + n;

    float acc[32];
    #pragma unroll
    for (int o = 0; o < 32; ++o) acc[o] = 0.f;

    for (int c = 0; c < 32; ++c) {
        float f = in[(size_t)c * HW];
        const float* wr = &Wt[chalf * 32 + c][0];
        #pragma unroll
        for (int o = 0; o < 32; o += 4) {
            float4 w4 = *(const float4*)(wr + o);
            acc[o]   += w4.x * f; acc[o+1] += w4.y * f;
            acc[o+2] += w4.z * f; acc[o+3] += w4.w * f;
        }
    }

    if (chalf) {
        #pragma unroll
        for (int o = 0; o < 32; ++o) comb[nl][o] = acc[o];
    }
    __syncthreads();
    if (chalf) return;

    #pragma unroll
    for (int o = 0; o < 32; ++o) acc[o] += comb[nl][o] + bias[o];

    if (!isP) {
        _Float16* dst = q_ws + ((size_t)(b * HW + n) << 5);
        #pragma unroll
        for (int g = 0; g < 4; ++g) {
            union { _Float16 h[8]; uint4 u; } pk;
            #pragma unroll
            for (int j = 0; j < 8; ++j) pk.h[j] = (_Float16)acc[g * 8 + j];
            *(uint4*)(dst + g * 8) = pk.u;
        }
    } else {
        int kt = n >> 5, ln = n & 31;
        #pragma unroll
        for (int chunk = 0; chunk < 2; ++chunk) {
            #pragma unroll
            for (int h2 = 0; h2 < 2; ++h2) {
                union { _Float16 h[8]; uint4 u; } pk;
                #pragma unroll
                for (int j = 0; j < 8; ++j) pk.h[j] = (_Float16)acc[chunk * 16 + h2 * 8 + j];
                size_t off = (((size_t)((b * 128 + kt) * 2 + chunk)) << 9) + (size_t)((h2 << 5) + ln) * 8;
                *(uint4*)(p_arr + off * 2) = pk.u;
            }
        }
    }
}

// A-fragment build: slot (hi, j) holds key kappa(hi,j) = 4hi + (j&3) + 8*(j>>2) =
// exactly the QK^T C-output key order; V prepped with the same map -> PV contracts
// correctly regardless of the hardware's internal k-slot ordering (bijection).
#define SOFTPART(S, A0, A1, LA, LB) { \
    float e0=fexp(S[0]),  e1=fexp(S[1]),  e2=fexp(S[2]),  e3=fexp(S[3]); \
    float e4=fexp(S[4]),  e5=fexp(S[5]),  e6=fexp(S[6]),  e7=fexp(S[7]); \
    float e8=fexp(S[8]),  e9=fexp(S[9]),  e10=fexp(S[10]), e11=fexp(S[11]); \
    float e12=fexp(S[12]), e13=fexp(S[13]), e14=fexp(S[14]), e15=fexp(S[15]); \
    LA += ((e0+e1)+(e2+e3)) + ((e4+e5)+(e6+e7)); \
    LB += ((e8+e9)+(e10+e11)) + ((e12+e13)+(e14+e15)); \
    A0 = make_uint4(cvtpk_bf16(e0,e1),  cvtpk_bf16(e2,e3),  cvtpk_bf16(e4,e5),  cvtpk_bf16(e6,e7)); \
    A1 = make_uint4(cvtpk_bf16(e8,e9),  cvtpk_bf16(e10,e11), cvtpk_bf16(e12,e13), cvtpk_bf16(e14,e15)); \
}

#define TILE(P0,P1,V00,V01,V10,V11) { \
    f32x16 s0 = (f32x16)0.0f, s1 = (f32x16)0.0f; \
    s0 = mfma16(P0, q00, s0); s0 = mfma16(P1, q01, s0); \
    s1 = mfma16(P0, q10, s1); s1 = mfma16(P1, q11, s1); \
    uint4 A0, A1; \
    SOFTPART(s0, A0, A1, l0a, l0b) \
    o00 = mfmab16(A0, V00, o00); o00 = mfmab16(A1, V01, o00); \
    o01 = mfmab16(A0, V10, o01); o01 = mfmab16(A1, V11, o01); \
    SOFTPART(s1, A0, A1, l1a, l1b) \
    o10 = mfmab16(A0, V00, o10); o10 = mfmab16(A1, V01, o10); \
    o11 = mfmab16(A0, V10, o11); o11 = mfmab16(A1, V11, o11); \
}

__global__ __launch_bounds__(512, 2) void attn_kernel(
    const _Float16* __restrict__ q_ws, const char* __restrict__ p_arr,
    const char* __restrict__ v_arr, float* __restrict__ out)
{
    __shared__ float part[8][32][33];
    __shared__ float l_red[8][2][64];
    __shared__ float l_inv[64];

    const int tid  = threadIdx.x;
    const int lane = tid & 63;
    const int w    = tid >> 6;       // wave = key split (512 keys each)
    const int lo5  = lane & 31;
    const int hi   = lane >> 5;

    // XCD-aware swizzle: id%8 = XCD (m09); XCD pair {2b,2b+1} <- batch b,
    // so each XCD's L2 holds one batch's ~1MB q/p/v working set.
    // Bijective: id bits [0]|[3:7] -> q-tile, bits [1:2] -> batch.
    const int id   = blockIdx.x + (blockIdx.y << 6);
    const int b    = (id >> 1) & 3;
    const int qb   = (((id >> 3) << 1) | (id & 1)) << 6;

    // Q fragments: 2 q-subtiles x 2 k-chunks, hoisted
    uint4 q00, q01, q10, q11;
    {
        const _Float16* qp = q_ws + (((size_t)(b * HW) + qb + lo5) << 5) + (hi << 3);
        q00 = *(const uint4*)qp;
        q01 = *(const uint4*)(qp + 16);
        q10 = *(const uint4*)(qp + 1024);
        q11 = *(const uint4*)(qp + 1040);
    }

    const char* pb = p_arr + ((size_t)(b * 128 + w * 16) << 11) + (lane << 4);
    const char* vb = v_arr + ((size_t)(b * 128 + w * 16) << 12) + (lane << 4);

    f32x16 o00 = (f32x16)0.0f, o01 = (f32x16)0.0f, o10 = (f32x16)0.0f, o11 = (f32x16)0.0f;
    float l0a = 0.f, l0b = 0.f, l1a = 0.f, l1b = 0.f;

    uint4 pA0, pA1, vA00, vA01, vA10, vA11;
    uint4 pB0, pB1, vB00, vB01, vB10, vB11;

#define LOADT(P0,P1,V00,V01,V10,V11,T) { \
    const char* pp = pb + ((size_t)(T) << 11); \
    P0 = *(const uint4*)pp; P1 = *(const uint4*)(pp + 1024); \
    const char* vp = vb + ((size_t)(T) << 12); \
    V00 = *(const uint4*)vp;          V01 = *(const uint4*)(vp + 1024); \
    V10 = *(const uint4*)(vp + 2048); V11 = *(const uint4*)(vp + 3072); }

    LOADT(pA0, pA1, vA00, vA01, vA10, vA11, 0)
    for (int i = 0; i < 8; ++i) {
        int t = 2 * i + 1;
        LOADT(pB0, pB1, vB00, vB01, vB10, vB11, t)
        TILE(pA0, pA1, vA00, vA01, vA10, vA11)
        int t2 = (t + 1 > 15) ? 15 : (t + 1);
        LOADT(pA0, pA1, vA00, vA01, vA10, vA11, t2)
        TILE(pB0, pB1, vB00, vB01, vB10, vB11)
    }

    // ---- epilogue: combine 8 key-split waves ----
    l_red[w][0][lane] = l0a + l0b;
    l_red[w][1][lane] = l1a + l1b;
    __syncthreads();
    if (tid < 64) {
        int s_ = tid >> 5, qq = tid & 31;
        float sum = 0.f;
        #pragma unroll
        for (int w2 = 0; w2 < 8; ++w2)
            sum += l_red[w2][s_][qq] + l_red[w2][s_][qq + 32];
        l_inv[tid] = 1.0f / sum;
    }

#define EPIPASS(OC, S_, H_) { \
    __syncthreads(); \
    _Pragma("unroll") \
    for (int r = 0; r < 16; ++r) \
        part[w][(r & 3) + 8 * (r >> 2) + 4 * hi][lo5] = OC[r]; \
    __syncthreads(); \
    _Pragma("unroll") \
    for (int rep = 0; rep < 2; ++rep) { \
        int idx = rep * 512 + tid; \
        int c_ = idx >> 5, q_ = idx & 31; \
        float v_ = ((part[0][q_][c_] + part[1][q_][c_]) + (part[2][q_][c_] + part[3][q_][c_])) \
                 + ((part[4][q_][c_] + part[5][q_][c_]) + (part[6][q_][c_] + part[7][q_][c_])); \
        out[((size_t)(((b << 6) + ((H_) << 5) + c_)) << 12) + qb + ((S_) << 5) + q_] = v_ * l_inv[((S_) << 5) + q_]; \
    } \
}

    EPIPASS(o00, 0, 0)
    EPIPASS(o01, 0, 1)
    EPIPASS(o10, 1, 0)
    EPIPASS(o11, 1, 1)
}

extern "C" void kernel_launch(void* const* d_in, const int* in_sizes, int n_in,
                              void* d_out, int out_size, void* d_ws, size_t ws_size,
                              hipStream_t stream)
{
    const float* Fq = (const float*)d_in[0];
    const float* Fp = (const float*)d_in[1];
    const float* W  = (const float*)d_in[2];
    const float* bs = (const float*)d_in[3];
    float* out = (float*)d_out;

    _Float16* q_ws = (_Float16*)d_ws;               // 1 MB
    char* p_arr = (char*)d_ws + (1 << 20);          // 1 MB
    char* v_arr = (char*)d_ws + (2 << 20);          // 2 MB

    prep_kernel<<<dim3(192, 4), 256, 0, stream>>>(Fq, Fp, W, bs, q_ws, p_arr, v_arr);
    attn_kernel<<<dim3(64, 4), 512, 0, stream>>>(q_ws, p_arr, v_arr, out);
}

// Round 8
// 30.215 us; speedup vs baseline: 16.0321x; 1.0171x over previous
//
#include <hip/hip_runtime.h>

#define HW 4096
#define LOG2E 1.44269504088896340736f

typedef _Float16 half8  __attribute__((ext_vector_type(8)));
typedef __bf16   bf16x8 __attribute__((ext_vector_type(8)));
typedef float    f32x16 __attribute__((ext_vector_type(16)));
typedef float    f32x2  __attribute__((ext_vector_type(2)));

// NOTE: __builtin_amdgcn_exp2f is empirically NOT 2^x here (rounds 2/4/5
// failed with identical absmax 3.479065 whenever used). OCML native exp2
// is the compiler-known bare v_exp_f32 path; v_exp_f32 itself is proven
// good on this data (rounds 1/7 via __expf, round 3/6 via exp2f).
extern "C" __device__ float __ocml_native_exp2_f32(float);
static __device__ __forceinline__ float fexp2(float x) {
    return __ocml_native_exp2_f32(x);
}

static __device__ __forceinline__ unsigned cvtpk_bf16(float lo, float hi) {
    unsigned r;
    asm("v_cvt_pk_bf16_f32 %0, %1, %2" : "=v"(r) : "v"(lo), "v"(hi));
    return r;
}

static __device__ __forceinline__ f32x16 mfma16(uint4 a, uint4 b, f32x16 c) {
    return __builtin_amdgcn_mfma_f32_32x32x16_f16(
        __builtin_bit_cast(half8, a), __builtin_bit_cast(half8, b), c, 0, 0, 0);
}
static __device__ __forceinline__ f32x16 mfmab16(uint4 a, uint4 b, f32x16 c) {
    return __builtin_amdgcn_mfma_f32_32x32x16_bf16(
        __builtin_bit_cast(bf16x8, a), __builtin_bit_cast(bf16x8, b), c, 0, 0, 0);
}

// ---- unified prep: grid (192, 4).
// x in [0,64): projection (x<32: q, else p), c-split-2, 128 n per block.
// x in [64,192): V B-fragment prep for tile mt = x-64, coalesced 16B stores.
// q is written PRESCALED by log2e (attn uses bare 2^x) — round-3-proven math.
__global__ __launch_bounds__(256) void prep_kernel(
    const float* __restrict__ Fq, const float* __restrict__ Fp,
    const float* __restrict__ W,  const float* __restrict__ bias,
    _Float16* __restrict__ q_ws, char* __restrict__ p_arr, char* __restrict__ v_arr)
{
    const int tid = threadIdx.x;
    const int b   = blockIdx.y;
    const int x   = blockIdx.x;

    if (x >= 64) {
        // ---- V prep: slot (hi,j) <- key 32*mt + 16*chunk + 4*hi + (j&3) + 8*(j>>2) ----
        int mt = x - 64;
        int c5 = tid & 31, hi = (tid >> 5) & 1, chunk = (tid >> 6) & 1, chalf = tid >> 7;
        int c = chalf * 32 + c5;
        int m = mt * 32 + chunk * 16 + hi * 4;
        const float* src = Fp + ((size_t)(b * 64 + c) << 12) + m;
        float4 f0 = *(const float4*)src;        // keys m..m+3   -> j=0..3
        float4 f1 = *(const float4*)(src + 8);  // keys m+8..m+11-> j=4..7
        uint4 o = make_uint4(cvtpk_bf16(f0.x, f0.y), cvtpk_bf16(f0.z, f0.w),
                             cvtpk_bf16(f1.x, f1.y), cvtpk_bf16(f1.z, f1.w));
        size_t tb = ((size_t)(((b * 128 + mt) * 2 + chalf) * 2 + chunk)) << 10;
        *(uint4*)(v_arr + tb + (size_t)((hi << 5) | c5) * 16) = o;   // consecutive lanes -> consecutive 16B
        return;
    }

    // ---- projection, c-split-2 ----
    __shared__ float Wt[64][36];     // transposed W, 16B-aligned rows, wave-uniform float4 reads
    __shared__ float comb[128][33];  // chalf-combine

    for (int i = tid; i < 2048; i += 256)
        Wt[i & 63][i >> 6] = W[i];   // W[o][c] flat: o=i>>6, c=i&63 (coalesced read)
    __syncthreads();

    const int isP   = x >> 5;
    const int nl    = tid & 127;
    const int chalf = tid >> 7;
    const int n     = ((x & 31) << 7) + nl;
    const float* in = (isP ? Fp : Fq) + (size_t)(b * 64 + chalf * 32) * HW + n;

    float acc[32];
    #pragma unroll
    for (int o = 0; o < 32; ++o) acc[o] = 0.f;

    for (int c = 0; c < 32; ++c) {
        float f = in[(size_t)c * HW];
        const float* wr = &Wt[chalf * 32 + c][0];
        #pragma unroll
        for (int o = 0; o < 32; o += 4) {
            float4 w4 = *(const float4*)(wr + o);
            acc[o]   += w4.x * f; acc[o+1] += w4.y * f;
            acc[o+2] += w4.z * f; acc[o+3] += w4.w * f;
        }
    }

    if (chalf) {
        #pragma unroll
        for (int o = 0; o < 32; ++o) comb[nl][o] = acc[o];
    }
    __syncthreads();
    if (chalf) return;

    #pragma unroll
    for (int o = 0; o < 32; ++o) acc[o] += comb[nl][o] + bias[o];

    if (!isP) {
        _Float16* dst = q_ws + ((size_t)(b * HW + n) << 5);
        #pragma unroll
        for (int g = 0; g < 4; ++g) {
            union { _Float16 h[8]; uint4 u; } pk;
            #pragma unroll
            for (int j = 0; j < 8; ++j) pk.h[j] = (_Float16)(acc[g * 8 + j] * LOG2E);
            *(uint4*)(dst + g * 8) = pk.u;
        }
    } else {
        int kt = n >> 5, ln = n & 31;
        #pragma unroll
        for (int chunk = 0; chunk < 2; ++chunk) {
            #pragma unroll
            for (int h2 = 0; h2 < 2; ++h2) {
                union { _Float16 h[8]; uint4 u; } pk;
                #pragma unroll
                for (int j = 0; j < 8; ++j) pk.h[j] = (_Float16)acc[chunk * 16 + h2 * 8 + j];
                size_t off = (((size_t)((b * 128 + kt) * 2 + chunk)) << 9) + (size_t)((h2 << 5) + ln) * 8;
                *(uint4*)(p_arr + off * 2) = pk.u;
            }
        }
    }
}

// A-fragment build: slot (hi, j) holds key kappa(hi,j) = 4hi + (j&3) + 8*(j>>2) =
// exactly the QK^T C-output key order; V prepped with the same map -> PV contracts
// correctly regardless of the hardware's internal k-slot ordering (bijection).
// l-sums via float2 (v_pk_add_f32); order of summation irrelevant.
#define SOFTPART(S, A0, A1, LV) { \
    float e0=fexp2(S[0]),  e1=fexp2(S[1]),  e2=fexp2(S[2]),  e3=fexp2(S[3]); \
    float e4=fexp2(S[4]),  e5=fexp2(S[5]),  e6=fexp2(S[6]),  e7=fexp2(S[7]); \
    float e8=fexp2(S[8]),  e9=fexp2(S[9]),  e10=fexp2(S[10]), e11=fexp2(S[11]); \
    float e12=fexp2(S[12]), e13=fexp2(S[13]), e14=fexp2(S[14]), e15=fexp2(S[15]); \
    f32x2 t0 = (f32x2){e0,e1}   + (f32x2){e2,e3}; \
    f32x2 t1 = (f32x2){e4,e5}   + (f32x2){e6,e7}; \
    f32x2 t2 = (f32x2){e8,e9}   + (f32x2){e10,e11}; \
    f32x2 t3 = (f32x2){e12,e13} + (f32x2){e14,e15}; \
    LV += (t0 + t1) + (t2 + t3); \
    A0 = make_uint4(cvtpk_bf16(e0,e1),  cvtpk_bf16(e2,e3),  cvtpk_bf16(e4,e5),  cvtpk_bf16(e6,e7)); \
    A1 = make_uint4(cvtpk_bf16(e8,e9),  cvtpk_bf16(e10,e11), cvtpk_bf16(e12,e13), cvtpk_bf16(e14,e15)); \
}

// Reordered: both SOFTPARTs first, then one 8-MFMA PV cluster (overlaps with
// the sibling wave's VALU phase), setprio(1) around the cluster (T5/m191).
#define TILE(P0,P1,V00,V01,V10,V11) { \
    f32x16 s0 = (f32x16)0.0f, s1 = (f32x16)0.0f; \
    s0 = mfma16(P0, q00, s0); s0 = mfma16(P1, q01, s0); \
    s1 = mfma16(P0, q10, s1); s1 = mfma16(P1, q11, s1); \
    uint4 A0, A1, B0, B1; \
    SOFTPART(s0, A0, A1, l0v) \
    SOFTPART(s1, B0, B1, l1v) \
    __builtin_amdgcn_s_setprio(1); \
    o00 = mfmab16(A0, V00, o00); o00 = mfmab16(A1, V01, o00); \
    o01 = mfmab16(A0, V10, o01); o01 = mfmab16(A1, V11, o01); \
    o10 = mfmab16(B0, V00, o10); o10 = mfmab16(B1, V01, o10); \
    o11 = mfmab16(B0, V10, o11); o11 = mfmab16(B1, V11, o11); \
    __builtin_amdgcn_s_setprio(0); \
}

__global__ __launch_bounds__(512, 2) void attn_kernel(
    const _Float16* __restrict__ q_ws, const char* __restrict__ p_arr,
    const char* __restrict__ v_arr, float* __restrict__ out)
{
    __shared__ float part[8][32][33];
    __shared__ float l_red[8][2][64];
    __shared__ float l_inv[64];

    const int tid  = threadIdx.x;
    const int lane = tid & 63;
    const int w    = tid >> 6;       // wave = key split (512 keys each)
    const int lo5  = lane & 31;
    const int hi   = lane >> 5;

    // XCD-aware swizzle: id%8 = XCD (m09); XCD pair {2b,2b+1} <- batch b.
    // Bijective: id bits [0]|[3:7] -> q-tile, bits [1:2] -> batch.
    const int id   = blockIdx.x + (blockIdx.y << 6);
    const int b    = (id >> 1) & 3;
    const int qb   = (((id >> 3) << 1) | (id & 1)) << 6;

    // Q fragments: 2 q-subtiles x 2 k-chunks, hoisted
    uint4 q00, q01, q10, q11;
    {
        const _Float16* qp = q_ws + (((size_t)(b * HW) + qb + lo5) << 5) + (hi << 3);
        q00 = *(const uint4*)qp;
        q01 = *(const uint4*)(qp + 16);
        q10 = *(const uint4*)(qp + 1024);
        q11 = *(const uint4*)(qp + 1040);
    }

    const char* pb = p_arr + ((size_t)(b * 128 + w * 16) << 11) + (lane << 4);
    const char* vb = v_arr + ((size_t)(b * 128 + w * 16) << 12) + (lane << 4);

    f32x16 o00 = (f32x16)0.0f, o01 = (f32x16)0.0f, o10 = (f32x16)0.0f, o11 = (f32x16)0.0f;
    f32x2 l0v = (f32x2){0.f, 0.f}, l1v = (f32x2){0.f, 0.f};

    uint4 pA0, pA1, vA00, vA01, vA10, vA11;
    uint4 pB0, pB1, vB00, vB01, vB10, vB11;

#define LOADT(P0,P1,V00,V01,V10,V11,T) { \
    const char* pp = pb + ((size_t)(T) << 11); \
    P0 = *(const uint4*)pp; P1 = *(const uint4*)(pp + 1024); \
    const char* vp = vb + ((size_t)(T) << 12); \
    V00 = *(const uint4*)vp;          V01 = *(const uint4*)(vp + 1024); \
    V10 = *(const uint4*)(vp + 2048); V11 = *(const uint4*)(vp + 3072); }

    LOADT(pA0, pA1, vA00, vA01, vA10, vA11, 0)
    for (int i = 0; i < 8; ++i) {
        int t = 2 * i + 1;
        LOADT(pB0, pB1, vB00, vB01, vB10, vB11, t)
        TILE(pA0, pA1, vA00, vA01, vA10, vA11)
        int t2 = (t + 1 > 15) ? 15 : (t + 1);
        LOADT(pA0, pA1, vA00, vA01, vA10, vA11, t2)
        TILE(pB0, pB1, vB00, vB01, vB10, vB11)
    }

    // ---- epilogue: combine 8 key-split waves ----
    l_red[w][0][lane] = l0v.x + l0v.y;
    l_red[w][1][lane] = l1v.x + l1v.y;
    __syncthreads();
    if (tid < 64) {
        int s_ = tid >> 5, qq = tid & 31;
        float sum = 0.f;
        #pragma unroll
        for (int w2 = 0; w2 < 8; ++w2)
            sum += l_red[w2][s_][qq] + l_red[w2][s_][qq + 32];
        l_inv[tid] = 1.0f / sum;
    }

#define EPIPASS(OC, S_, H_) { \
    __syncthreads(); \
    _Pragma("unroll") \
    for (int r = 0; r < 16; ++r) \
        part[w][(r & 3) + 8 * (r >> 2) + 4 * hi][lo5] = OC[r]; \
    __syncthreads(); \
    _Pragma("unroll") \
    for (int rep = 0; rep < 2; ++rep) { \
        int idx = rep * 512 + tid; \
        int c_ = idx >> 5, q_ = idx & 31; \
        float v_ = ((part[0][q_][c_] + part[1][q_][c_]) + (part[2][q_][c_] + part[3][q_][c_])) \
                 + ((part[4][q_][c_] + part[5][q_][c_]) + (part[6][q_][c_] + part[7][q_][c_])); \
        out[((size_t)(((b << 6) + ((H_) << 5) + c_)) << 12) + qb + ((S_) << 5) + q_] = v_ * l_inv[((S_) << 5) + q_]; \
    } \
}

    EPIPASS(o00, 0, 0)
    EPIPASS(o01, 0, 1)
    EPIPASS(o10, 1, 0)
    EPIPASS(o11, 1, 1)
}

extern "C" void kernel_launch(void* const* d_in, const int* in_sizes, int n_in,
                              void* d_out, int out_size, void* d_ws, size_t ws_size,
                              hipStream_t stream)
{
    const float* Fq = (const float*)d_in[0];
    const float* Fp = (const float*)d_in[1];
    const float* W  = (const float*)d_in[2];
    const float* bs = (const float*)d_in[3];
    float* out = (float*)d_out;

    _Float16* q_ws = (_Float16*)d_ws;               // 1 MB
    char* p_arr = (char*)d_ws + (1 << 20);          // 1 MB
    char* v_arr = (char*)d_ws + (2 << 20);          // 2 MB

    prep_kernel<<<dim3(192, 4), 256, 0, stream>>>(Fq, Fp, W, bs, q_ws, p_arr, v_arr);
    attn_kernel<<<dim3(64, 4), 512, 0, stream>>>(q_ws, p_arr, v_arr, out);
}